// Round 8
// baseline (226.419 us; speedup 1.0000x reference)
//
#include <hip/hip_runtime.h>

typedef unsigned int uint;

#define N_NODES 50000
#define N_EDGES 1600000
#define DIM 128
#define LN_EPS 1e-10f

#define ROWS_PER_BUCKET 64
#define N_BUCKETS 782            // ceil(50000/64)
#define BUCKET_CAP 2560          // mean 2048, +11 sigma
#define EPB 4096                 // edges per scatter block
#define SB 391                   // scatter blocks
#define FCB 6250                 // feat-convert blocks
#define GPAD 16                  // gcnt stride in ints (64 B -> 1 counter/line)
#define CAPR 76                  // per-row list slots (mean 32, p_overflow ~4e-10/row)

__device__ __forceinline__ uint f2bf(float x) {
    uint u = __float_as_uint(x);
    return (u + 0x7FFFu + ((u >> 16) & 1u)) >> 16;   // RNE to bf16
}

// ---------------------------------------------------------------------------
// prep = bucket_scatter (blocks [0,SB)) + feat->bf16 convert + W pack.
// Scatter: LDS histogram + row stash -> ONE padded global atomic per
// (block,bucket) -- gcnt strided 64 B so the 306K atomics hit 782 distinct
// L2 lines (391/line) instead of 49 (6.2K/line serialized = R7's ~80 us wall).
// ---------------------------------------------------------------------------
__global__ __launch_bounds__(256) void prep(
    const float* __restrict__ feat, const float* __restrict__ W,
    const int* __restrict__ rows, const int* __restrict__ cols,
    const float* __restrict__ vals, int* __restrict__ gcnt,
    int2* __restrict__ perm, uint* __restrict__ featb_u,
    uint* __restrict__ wpk_u)
{
    __shared__ int cnt[N_BUCKETS];
    __shared__ int gbase[N_BUCKETS];
    __shared__ int lcur[N_BUCKETS];
    __shared__ int stash[EPB];          // 16 KB
    const int bx = blockIdx.x;
    const int t  = threadIdx.x;

    if (bx >= SB) {
        int cb = bx - SB;
        if (cb < FCB) {                 // feat fp32 -> packed bf16
            int i = cb * 256 + t;
            float4 v = ((const float4*)feat)[i];
            ((uint2*)featb_u)[i] = make_uint2(
                f2bf(v.x) | (f2bf(v.y) << 16),
                f2bf(v.z) | (f2bf(v.w) << 16));
        } else {                        // W pack (one block)
            for (int idx = t; idx < 8192; idx += 256) {
                int g = idx >> 8, rem = idx & 255;
                int l = rem >> 2, k = rem & 3, i = 4 * g + k;
                wpk_u[idx] = f2bf(W[l * DIM + i]) |
                             (f2bf(W[(l + 64) * DIM + i]) << 16);
            }
        }
        return;
    }

    for (int i = t; i < N_BUCKETS; i += 256) { cnt[i] = 0; lcur[i] = 0; }
    __syncthreads();

    const int base = bx * EPB;
    for (int k = 0; k < EPB; k += 256) {
        int e = base + k + t;
        int r = (e < N_EDGES) ? rows[e] : -1;
        stash[k + t] = r;
        if (r >= 0) atomicAdd(&cnt[r >> 6], 1);
    }
    __syncthreads();

    for (int i = t; i < N_BUCKETS; i += 256) {
        int c = cnt[i];
        gbase[i] = c ? atomicAdd(&gcnt[i * GPAD], c) : 0;
    }
    __syncthreads();

    for (int k = 0; k < EPB; k += 256) {
        int e = base + k + t;
        int r = stash[k + t];
        if (r >= 0) {
            int b = r >> 6;
            int rank = atomicAdd(&lcur[b], 1);
            int pos = gbase[b] + rank;
            if (pos < BUCKET_CAP)       // statistically impossible; safety
                perm[(size_t)b * BUCKET_CAP + pos] =
                    make_int2(cols[e] | ((r & 63) << 16), __float_as_int(vals[e]));
        }
    }
}

// ---------------------------------------------------------------------------
// agg_fused: 2 blocks per bucket (512 thr, 32 rows each; grid 1564).
// Phase 1: SINGLE coalesced pass over the bucket, compacting into 32 per-row
// LDS lists (CAPR slots each) -- replaces R7's count+scan+compact (half the
// perm reads, one fewer barrier round).
// Phase 2: 4 rows/wave, bf16 gathers, unroll-8 ILP, fp32 reg accumulators.
// Phase 3: rows -> LDS (overlaying dead lists).
// Phase 4: 128x128 linear (packed-bf16 W in 32 KB LDS) + ReLU + LN -> out.
// LDS ~52.4 KB -> 3 blocks/CU = 24 waves/CU.
// ---------------------------------------------------------------------------
__global__ __launch_bounds__(512, 6) void agg_fused(
    const int2* __restrict__ perm, const int* __restrict__ gcnt,
    const unsigned short* __restrict__ featb, const uint4* __restrict__ wpk,
    const float* __restrict__ bias, const float* __restrict__ scale,
    const float* __restrict__ offset, float* __restrict__ out)
{
    __shared__ int2  lists[32 * CAPR];    // 19456 B; rowsbuf (16384 B) overlays
    __shared__ uint4 sW[2048];            // 32 KB packed-bf16 W
    __shared__ int   lcnt[32];

    const int t = threadIdx.x;
    for (int i = t; i < 2048; i += 512) sW[i] = wpk[i];

    float* rowsbuf = (float*)lists;

    const int b  = blockIdx.x >> 1;
    const int lo = (blockIdx.x & 1) * 32;
    if (t < 32) lcnt[t] = 0;
    __syncthreads();

    int n = gcnt[b * GPAD];
    if (n > BUCKET_CAP) n = BUCKET_CAP;
    const int2* pb = perm + (size_t)b * BUCKET_CAP;

    for (int e = t; e < n; e += 512) {
        int2 p = pb[e];
        int rl = ((p.x >> 16) & 63) - lo;
        if ((uint)rl < 32u) {
            int pos = atomicAdd(&lcnt[rl], 1);
            if (pos < CAPR)
                lists[rl * CAPR + pos] = make_int2(p.x & 0xFFFF, p.y);
        }
    }
    __syncthreads();

    const int lane = t & 63;
    const int wid  = t >> 6;        // 0..7
    const int rb   = wid * 4;       // first local row of this wave

    float ax[4], ay[4];
    #pragma unroll
    for (int j = 0; j < 4; ++j) {
        int rl = rb + j;
        int cnt = lcnt[rl];
        if (cnt > CAPR) cnt = CAPR;
        const int2* L = &lists[rl * CAPR];
        float sx = 0.f, sy = 0.f;
        int e = 0;
        for (; e + 7 < cnt; e += 8) {
            int2 p[8]; uint g[8];
            #pragma unroll
            for (int k = 0; k < 8; ++k) p[k] = L[e + k];
            #pragma unroll
            for (int k = 0; k < 8; ++k)
                g[k] = ((const uint*)(featb + (size_t)p[k].x * DIM))[lane];
            #pragma unroll
            for (int k = 0; k < 8; ++k) {
                float v = __int_as_float(p[k].y);
                sx = fmaf(v, __uint_as_float(g[k] << 16), sx);
                sy = fmaf(v, __uint_as_float(g[k] & 0xFFFF0000u), sy);
            }
        }
        for (; e < cnt; ++e) {
            int2 p = L[e];
            uint g = ((const uint*)(featb + (size_t)p.x * DIM))[lane];
            float v = __int_as_float(p.y);
            sx = fmaf(v, __uint_as_float(g << 16), sx);
            sy = fmaf(v, __uint_as_float(g & 0xFFFF0000u), sy);
        }
        ax[j] = sx; ay[j] = sy;
    }
    __syncthreads();               // lists dead -> reuse as rowsbuf

    #pragma unroll
    for (int j = 0; j < 4; ++j)
        ((float2*)rowsbuf)[(rb + j) * 64 + lane] = make_float2(ax[j], ay[j]);
    __syncthreads();

    // ---- phase 4: linear + ReLU + LN for this wave's 4 rows ----
    const float bb0 = bias[lane],   bb1 = bias[lane + 64];
    const float sc0 = scale[lane],  sc1 = scale[lane + 64];
    const float of0 = offset[lane], of1 = offset[lane + 64];

    const float4* R0 = (const float4*)(rowsbuf + (rb + 0) * DIM);
    const float4* R1 = (const float4*)(rowsbuf + (rb + 1) * DIM);
    const float4* R2 = (const float4*)(rowsbuf + (rb + 2) * DIM);
    const float4* R3 = (const float4*)(rowsbuf + (rb + 3) * DIM);

    float x0 = bb0, y0 = bb1, x1 = bb0, y1 = bb1;
    float x2 = bb0, y2 = bb1, x3 = bb0, y3 = bb1;

    #pragma unroll 8
    for (int g = 0; g < 32; ++g) {
        uint4 wv = sW[g * 64 + lane];
        float4 a0 = R0[g], a1 = R1[g], a2 = R2[g], a3 = R3[g];
        float w0, w1;
        w0 = __uint_as_float(wv.x << 16); w1 = __uint_as_float(wv.x & 0xFFFF0000u);
        x0 = fmaf(a0.x, w0, x0);  y0 = fmaf(a0.x, w1, y0);
        x1 = fmaf(a1.x, w0, x1);  y1 = fmaf(a1.x, w1, y1);
        x2 = fmaf(a2.x, w0, x2);  y2 = fmaf(a2.x, w1, y2);
        x3 = fmaf(a3.x, w0, x3);  y3 = fmaf(a3.x, w1, y3);
        w0 = __uint_as_float(wv.y << 16); w1 = __uint_as_float(wv.y & 0xFFFF0000u);
        x0 = fmaf(a0.y, w0, x0);  y0 = fmaf(a0.y, w1, y0);
        x1 = fmaf(a1.y, w0, x1);  y1 = fmaf(a1.y, w1, y1);
        x2 = fmaf(a2.y, w0, x2);  y2 = fmaf(a2.y, w1, y2);
        x3 = fmaf(a3.y, w0, x3);  y3 = fmaf(a3.y, w1, y3);
        w0 = __uint_as_float(wv.z << 16); w1 = __uint_as_float(wv.z & 0xFFFF0000u);
        x0 = fmaf(a0.z, w0, x0);  y0 = fmaf(a0.z, w1, y0);
        x1 = fmaf(a1.z, w0, x1);  y1 = fmaf(a1.z, w1, y1);
        x2 = fmaf(a2.z, w0, x2);  y2 = fmaf(a2.z, w1, y2);
        x3 = fmaf(a3.z, w0, x3);  y3 = fmaf(a3.z, w1, y3);
        w0 = __uint_as_float(wv.w << 16); w1 = __uint_as_float(wv.w & 0xFFFF0000u);
        x0 = fmaf(a0.w, w0, x0);  y0 = fmaf(a0.w, w1, y0);
        x1 = fmaf(a1.w, w0, x1);  y1 = fmaf(a1.w, w1, y1);
        x2 = fmaf(a2.w, w0, x2);  y2 = fmaf(a2.w, w1, y2);
        x3 = fmaf(a3.w, w0, x3);  y3 = fmaf(a3.w, w1, y3);
    }

    #pragma unroll
    for (int j = 0; j < 4; ++j) {
        int r = b * ROWS_PER_BUCKET + lo + rb + j;
        if (r >= N_NODES) continue;                       // wave-uniform
        float A0 = (j == 0) ? x0 : (j == 1) ? x1 : (j == 2) ? x2 : x3;
        float A1 = (j == 0) ? y0 : (j == 1) ? y1 : (j == 2) ? y2 : y3;
        A0 = fmaxf(A0, 0.0f);
        A1 = fmaxf(A1, 0.0f);

        float s = A0 + A1;
        #pragma unroll
        for (int off = 32; off >= 1; off >>= 1) s += __shfl_xor(s, off, 64);
        float mean = s * (1.0f / 128.0f);

        float d0 = A0 - mean, d1 = A1 - mean;
        float q = d0 * d0 + d1 * d1;
        #pragma unroll
        for (int off = 32; off >= 1; off >>= 1) q += __shfl_xor(q, off, 64);
        float rstd = rsqrtf(q * (1.0f / 128.0f) + LN_EPS);

        size_t rowp = (size_t)r * DIM;
        out[rowp + lane]      = d0 * sc0 * rstd + of0;
        out[rowp + lane + 64] = d1 * sc1 * rstd + of1;
    }
}

extern "C" void kernel_launch(void* const* d_in, const int* in_sizes, int n_in,
                              void* d_out, int out_size, void* d_ws, size_t ws_size,
                              hipStream_t stream) {
    const float* feat_in = (const float*)d_in[0];
    const int*   rows    = (const int*)d_in[1];
    const int*   cols    = (const int*)d_in[2];
    const float* vals    = (const float*)d_in[3];
    const float* W       = (const float*)d_in[4];
    const float* bias    = (const float*)d_in[5];
    const float* scale   = (const float*)d_in[6];
    const float* offset  = (const float*)d_in[7];
    float* out = (float*)d_out;

    // ---- workspace layout ----
    char* p = (char*)d_ws;
    int2* perm = (int2*)p;                 p += (size_t)N_BUCKETS * BUCKET_CAP * 8; // 16.0 MB
    unsigned short* featb = (unsigned short*)p;
                                           p += (size_t)N_NODES * DIM * 2;          // 12.8 MB
    uint* wpk = (uint*)p;                  p += 32768;                              // 32 KB
    int*  gcnt = (int*)p;                  p += (size_t)N_BUCKETS * GPAD * 4;       // 50 KB padded

    hipMemsetAsync(gcnt, 0, (size_t)N_BUCKETS * GPAD * sizeof(int), stream);

    prep<<<SB + FCB + 1, 256, 0, stream>>>(feat_in, W, rows, cols, vals,
                                           gcnt, perm, (uint*)featb, wpk);
    agg_fused<<<N_BUCKETS * 2, 512, 0, stream>>>(perm, gcnt, featb,
                                                 (const uint4*)wpk,
                                                 bias, scale, offset, out);
}

// Round 9
// 214.898 us; speedup vs baseline: 1.0536x; 1.0536x over previous
//
#include <hip/hip_runtime.h>

typedef unsigned int uint;

#define N_NODES 50000
#define N_EDGES 1600000
#define DIM 128
#define LN_EPS 1e-10f

#define ROWS_PER_BUCKET 64
#define N_BUCKETS 782            // ceil(50000/64)
#define BUCKET_CAP 2560          // mean 2048, +11 sigma
#define EPB 4096                 // edges per scatter block
#define SB 391                   // scatter blocks
#define FCB 1563                 // feat-convert blocks (1024 thr, 1 float4 each)
#define GPAD 16                  // gcnt stride in ints (64 B/counter)
#define CAPR 76                  // per-row list slots (mean 32, +11 sigma)

__device__ __forceinline__ uint f2bf(float x) {
    uint u = __float_as_uint(x);
    return (u + 0x7FFFu + ((u >> 16) & 1u)) >> 16;   // RNE to bf16
}

// ---------------------------------------------------------------------------
// prep = bucket_scatter (blocks [0,SB)) + feat->bf16 convert + W pack.
// R8 post-mortem: scatter was LATENCY-bound at 1.5 blocks/CU (~6 waves) --
// the atomic-line theory was wrong.  Fix: 1024-thread scatter blocks (same
// EPB) -> 16 waves/block, ~24 waves/CU of latency hiding for the scattered
// perm writes and LDS atomic chains.
// ---------------------------------------------------------------------------
__global__ __launch_bounds__(1024) void prep(
    const float* __restrict__ feat, const float* __restrict__ W,
    const int* __restrict__ rows, const int* __restrict__ cols,
    const float* __restrict__ vals, int* __restrict__ gcnt,
    int2* __restrict__ perm, uint* __restrict__ featb_u,
    uint* __restrict__ wpk_u)
{
    __shared__ int cnt[N_BUCKETS];
    __shared__ int gbase[N_BUCKETS];
    __shared__ int lcur[N_BUCKETS];
    __shared__ int stash[EPB];          // 16 KB
    const int bx = blockIdx.x;
    const int t  = threadIdx.x;

    if (bx >= SB) {
        int cb = bx - SB;
        if (cb < FCB) {                 // feat fp32 -> packed bf16
            int i = cb * 1024 + t;      // float4 index, 1.6M total
            if (i < N_NODES * DIM / 4) {
                float4 v = ((const float4*)feat)[i];
                ((uint2*)featb_u)[i] = make_uint2(
                    f2bf(v.x) | (f2bf(v.y) << 16),
                    f2bf(v.z) | (f2bf(v.w) << 16));
            }
        } else {                        // W pack (one block)
            for (int idx = t; idx < 8192; idx += 1024) {
                int g = idx >> 8, rem = idx & 255;
                int l = rem >> 2, k = rem & 3, i = 4 * g + k;
                wpk_u[idx] = f2bf(W[l * DIM + i]) |
                             (f2bf(W[(l + 64) * DIM + i]) << 16);
            }
        }
        return;
    }

    for (int i = t; i < N_BUCKETS; i += 1024) { cnt[i] = 0; lcur[i] = 0; }
    __syncthreads();

    const int base = bx * EPB;
    for (int k = 0; k < EPB; k += 1024) {
        int e = base + k + t;
        int r = (e < N_EDGES) ? rows[e] : -1;
        stash[k + t] = r;
        if (r >= 0) atomicAdd(&cnt[r >> 6], 1);
    }
    __syncthreads();

    for (int i = t; i < N_BUCKETS; i += 1024) {
        int c = cnt[i];
        gbase[i] = c ? atomicAdd(&gcnt[i * GPAD], c) : 0;
    }
    __syncthreads();

    for (int k = 0; k < EPB; k += 1024) {
        int e = base + k + t;
        int r = stash[k + t];
        if (r >= 0) {
            int b = r >> 6;
            int rank = atomicAdd(&lcur[b], 1);
            int pos = gbase[b] + rank;
            if (pos < BUCKET_CAP)       // statistically impossible; safety
                perm[(size_t)b * BUCKET_CAP + pos] =
                    make_int2(cols[e] | ((r & 63) << 16), __float_as_int(vals[e]));
        }
    }
}

// ---------------------------------------------------------------------------
// agg_fused: 2 blocks per bucket (512 thr, 32 rows each; grid 1564).
// Phase 1: single coalesced pass compacting into 32 per-row LDS lists.
// Phase 2: 4 rows/wave, bf16 gathers, unroll-8 ILP, fp32 reg accumulators.
// Phase 3: rows -> LDS (overlaying dead lists).
// Phase 4: 128x128 linear (packed-bf16 W in 32 KB LDS) + ReLU + LN -> out.
// ---------------------------------------------------------------------------
__global__ __launch_bounds__(512, 6) void agg_fused(
    const int2* __restrict__ perm, const int* __restrict__ gcnt,
    const unsigned short* __restrict__ featb, const uint4* __restrict__ wpk,
    const float* __restrict__ bias, const float* __restrict__ scale,
    const float* __restrict__ offset, float* __restrict__ out)
{
    __shared__ int2  lists[32 * CAPR];    // 19456 B; rowsbuf (16 KB) overlays
    __shared__ uint4 sW[2048];            // 32 KB packed-bf16 W
    __shared__ int   lcnt[32];

    const int t = threadIdx.x;
    for (int i = t; i < 2048; i += 512) sW[i] = wpk[i];

    float* rowsbuf = (float*)lists;

    const int b  = blockIdx.x >> 1;
    const int lo = (blockIdx.x & 1) * 32;
    if (t < 32) lcnt[t] = 0;
    __syncthreads();

    int n = gcnt[b * GPAD];
    if (n > BUCKET_CAP) n = BUCKET_CAP;
    const int2* pb = perm + (size_t)b * BUCKET_CAP;

    for (int e = t; e < n; e += 512) {
        int2 p = pb[e];
        int rl = ((p.x >> 16) & 63) - lo;
        if ((uint)rl < 32u) {
            int pos = atomicAdd(&lcnt[rl], 1);
            if (pos < CAPR)
                lists[rl * CAPR + pos] = make_int2(p.x & 0xFFFF, p.y);
        }
    }
    __syncthreads();

    const int lane = t & 63;
    const int wid  = t >> 6;        // 0..7
    const int rb   = wid * 4;       // first local row of this wave

    float ax[4], ay[4];
    #pragma unroll
    for (int j = 0; j < 4; ++j) {
        int rl = rb + j;
        int cnt = lcnt[rl];
        if (cnt > CAPR) cnt = CAPR;
        const int2* L = &lists[rl * CAPR];
        float sx = 0.f, sy = 0.f;
        int e = 0;
        for (; e + 7 < cnt; e += 8) {
            int2 p[8]; uint g[8];
            #pragma unroll
            for (int k = 0; k < 8; ++k) p[k] = L[e + k];
            #pragma unroll
            for (int k = 0; k < 8; ++k)
                g[k] = ((const uint*)(featb + (size_t)p[k].x * DIM))[lane];
            #pragma unroll
            for (int k = 0; k < 8; ++k) {
                float v = __int_as_float(p[k].y);
                sx = fmaf(v, __uint_as_float(g[k] << 16), sx);
                sy = fmaf(v, __uint_as_float(g[k] & 0xFFFF0000u), sy);
            }
        }
        for (; e < cnt; ++e) {
            int2 p = L[e];
            uint g = ((const uint*)(featb + (size_t)p.x * DIM))[lane];
            float v = __int_as_float(p.y);
            sx = fmaf(v, __uint_as_float(g << 16), sx);
            sy = fmaf(v, __uint_as_float(g & 0xFFFF0000u), sy);
        }
        ax[j] = sx; ay[j] = sy;
    }
    __syncthreads();               // lists dead -> reuse as rowsbuf

    #pragma unroll
    for (int j = 0; j < 4; ++j)
        ((float2*)rowsbuf)[(rb + j) * 64 + lane] = make_float2(ax[j], ay[j]);
    __syncthreads();

    // ---- phase 4: linear + ReLU + LN for this wave's 4 rows ----
    const float bb0 = bias[lane],   bb1 = bias[lane + 64];
    const float sc0 = scale[lane],  sc1 = scale[lane + 64];
    const float of0 = offset[lane], of1 = offset[lane + 64];

    const float4* R0 = (const float4*)(rowsbuf + (rb + 0) * DIM);
    const float4* R1 = (const float4*)(rowsbuf + (rb + 1) * DIM);
    const float4* R2 = (const float4*)(rowsbuf + (rb + 2) * DIM);
    const float4* R3 = (const float4*)(rowsbuf + (rb + 3) * DIM);

    float x0 = bb0, y0 = bb1, x1 = bb0, y1 = bb1;
    float x2 = bb0, y2 = bb1, x3 = bb0, y3 = bb1;

    #pragma unroll 8
    for (int g = 0; g < 32; ++g) {
        uint4 wv = sW[g * 64 + lane];
        float4 a0 = R0[g], a1 = R1[g], a2 = R2[g], a3 = R3[g];
        float w0, w1;
        w0 = __uint_as_float(wv.x << 16); w1 = __uint_as_float(wv.x & 0xFFFF0000u);
        x0 = fmaf(a0.x, w0, x0);  y0 = fmaf(a0.x, w1, y0);
        x1 = fmaf(a1.x, w0, x1);  y1 = fmaf(a1.x, w1, y1);
        x2 = fmaf(a2.x, w0, x2);  y2 = fmaf(a2.x, w1, y2);
        x3 = fmaf(a3.x, w0, x3);  y3 = fmaf(a3.x, w1, y3);
        w0 = __uint_as_float(wv.y << 16); w1 = __uint_as_float(wv.y & 0xFFFF0000u);
        x0 = fmaf(a0.y, w0, x0);  y0 = fmaf(a0.y, w1, y0);
        x1 = fmaf(a1.y, w0, x1);  y1 = fmaf(a1.y, w1, y1);
        x2 = fmaf(a2.y, w0, x2);  y2 = fmaf(a2.y, w1, y2);
        x3 = fmaf(a3.y, w0, x3);  y3 = fmaf(a3.y, w1, y3);
        w0 = __uint_as_float(wv.z << 16); w1 = __uint_as_float(wv.z & 0xFFFF0000u);
        x0 = fmaf(a0.z, w0, x0);  y0 = fmaf(a0.z, w1, y0);
        x1 = fmaf(a1.z, w0, x1);  y1 = fmaf(a1.z, w1, y1);
        x2 = fmaf(a2.z, w0, x2);  y2 = fmaf(a2.z, w1, y2);
        x3 = fmaf(a3.z, w0, x3);  y3 = fmaf(a3.z, w1, y3);
        w0 = __uint_as_float(wv.w << 16); w1 = __uint_as_float(wv.w & 0xFFFF0000u);
        x0 = fmaf(a0.w, w0, x0);  y0 = fmaf(a0.w, w1, y0);
        x1 = fmaf(a1.w, w0, x1);  y1 = fmaf(a1.w, w1, y1);
        x2 = fmaf(a2.w, w0, x2);  y2 = fmaf(a2.w, w1, y2);
        x3 = fmaf(a3.w, w0, x3);  y3 = fmaf(a3.w, w1, y3);
    }

    #pragma unroll
    for (int j = 0; j < 4; ++j) {
        int r = b * ROWS_PER_BUCKET + lo + rb + j;
        if (r >= N_NODES) continue;                       // wave-uniform
        float A0 = (j == 0) ? x0 : (j == 1) ? x1 : (j == 2) ? x2 : x3;
        float A1 = (j == 0) ? y0 : (j == 1) ? y1 : (j == 2) ? y2 : y3;
        A0 = fmaxf(A0, 0.0f);
        A1 = fmaxf(A1, 0.0f);

        float s = A0 + A1;
        #pragma unroll
        for (int off = 32; off >= 1; off >>= 1) s += __shfl_xor(s, off, 64);
        float mean = s * (1.0f / 128.0f);

        float d0 = A0 - mean, d1 = A1 - mean;
        float q = d0 * d0 + d1 * d1;
        #pragma unroll
        for (int off = 32; off >= 1; off >>= 1) q += __shfl_xor(q, off, 64);
        float rstd = rsqrtf(q * (1.0f / 128.0f) + LN_EPS);

        size_t rowp = (size_t)r * DIM;
        out[rowp + lane]      = d0 * sc0 * rstd + of0;
        out[rowp + lane + 64] = d1 * sc1 * rstd + of1;
    }
}

extern "C" void kernel_launch(void* const* d_in, const int* in_sizes, int n_in,
                              void* d_out, int out_size, void* d_ws, size_t ws_size,
                              hipStream_t stream) {
    const float* feat_in = (const float*)d_in[0];
    const int*   rows    = (const int*)d_in[1];
    const int*   cols    = (const int*)d_in[2];
    const float* vals    = (const float*)d_in[3];
    const float* W       = (const float*)d_in[4];
    const float* bias    = (const float*)d_in[5];
    const float* scale   = (const float*)d_in[6];
    const float* offset  = (const float*)d_in[7];
    float* out = (float*)d_out;

    // ---- workspace layout ----
    char* p = (char*)d_ws;
    int2* perm = (int2*)p;                 p += (size_t)N_BUCKETS * BUCKET_CAP * 8; // 16.0 MB
    unsigned short* featb = (unsigned short*)p;
                                           p += (size_t)N_NODES * DIM * 2;          // 12.8 MB
    uint* wpk = (uint*)p;                  p += 32768;                              // 32 KB
    int*  gcnt = (int*)p;                  p += (size_t)N_BUCKETS * GPAD * 4;       // 50 KB padded

    hipMemsetAsync(gcnt, 0, (size_t)N_BUCKETS * GPAD * sizeof(int), stream);

    prep<<<SB + FCB + 1, 1024, 0, stream>>>(feat_in, W, rows, cols, vals,
                                            gcnt, perm, (uint*)featb, wpk);
    agg_fused<<<N_BUCKETS * 2, 512, 0, stream>>>(perm, gcnt, featb,
                                                 (const uint4*)wpk,
                                                 bias, scale, offset, out);
}

// Round 10
// 193.073 us; speedup vs baseline: 1.1727x; 1.1130x over previous
//
#include <hip/hip_runtime.h>

typedef unsigned int uint;

#define N_NODES 50000
#define N_EDGES 1600000
#define DIM 128
#define LN_EPS 1e-10f

#define ROWS_PER_BUCKET 64
#define N_BUCKETS 782            // ceil(50000/64)
#define BUCKET_CAP 2560          // mean 2048, +11 sigma
#define EPB 8192                 // edges per scatter block
#define SB 196                   // scatter blocks (196*8192 >= 1.6M)
#define FCB 1563                 // feat-convert blocks (1024 thr, 1 float4 each)
#define GPAD 16                  // gcnt stride in ints (64 B/counter)
#define CAPR 76                  // per-row agg list slots (mean 32, +11 sigma)

__device__ __forceinline__ uint f2bf(float x) {
    uint u = __float_as_uint(x);
    return (u + 0x7FFFu + ((u >> 16) & 1u)) >> 16;   // RNE to bf16
}

// ---------------------------------------------------------------------------
// prep = bucket_scatter + feat->bf16 convert + W pack.
// R9 post-mortem: scatter's wall is the per-thread scattered 8-B perm stores
// (64 lanes -> 64 buckets per instruction).  Fix: stage the block's 8192
// entries in LDS grouped by bucket (LDS scan of the histogram gives group
// bases; bucket id packed in bits 22..31 of .x), then FLUSH IN SLOT ORDER --
// consecutive slots of a group have consecutive perm destinations, so the
// flush is coalesced 512-B streams instead of random 8-B stores.
// ---------------------------------------------------------------------------
__global__ __launch_bounds__(1024) void prep(
    const float* __restrict__ feat, const float* __restrict__ W,
    const int* __restrict__ rows, const int* __restrict__ cols,
    const float* __restrict__ vals, int* __restrict__ gcnt,
    int2* __restrict__ perm, uint* __restrict__ featb_u,
    uint* __restrict__ wpk_u)
{
    __shared__ int  cnt[N_BUCKETS];
    __shared__ int  gbase[N_BUCKETS];
    __shared__ int  lbase[N_BUCKETS];
    __shared__ int  lcur[N_BUCKETS];
    __shared__ int  csum[64];
    __shared__ int2 stageE[EPB];        // 64 KB
    const int bx = blockIdx.x;
    const int t  = threadIdx.x;

    if (bx >= SB) {
        int cb = bx - SB;
        if (cb < FCB) {                 // feat fp32 -> packed bf16
            int i = cb * 1024 + t;
            if (i < N_NODES * DIM / 4) {
                float4 v = ((const float4*)feat)[i];
                ((uint2*)featb_u)[i] = make_uint2(
                    f2bf(v.x) | (f2bf(v.y) << 16),
                    f2bf(v.z) | (f2bf(v.w) << 16));
            }
        } else {                        // W pack (one block)
            for (int idx = t; idx < 8192; idx += 1024) {
                int g = idx >> 8, rem = idx & 255;
                int l = rem >> 2, k = rem & 3, i = 4 * g + k;
                wpk_u[idx] = f2bf(W[l * DIM + i]) |
                             (f2bf(W[(l + 64) * DIM + i]) << 16);
            }
        }
        return;
    }

    // ---- phase A: block histogram ----
    for (int i = t; i < N_BUCKETS; i += 1024) cnt[i] = 0;
    __syncthreads();
    const int base = bx * EPB;
    for (int k = 0; k < EPB; k += 1024) {
        int e = base + k + t;
        if (e < N_EDGES) atomicAdd(&cnt[rows[e] >> 6], 1);
    }
    __syncthreads();

    // ---- phase B: global reservation + LDS exclusive scan (64x13 chunks) ----
    for (int i = t; i < N_BUCKETS; i += 1024) {
        int c = cnt[i];
        gbase[i] = c ? atomicAdd(&gcnt[i * GPAD], c) : 0;
    }
    if (t < 64) {
        int s = 0;
        for (int j = 0; j < 13; ++j) {
            int idx = t * 13 + j;
            if (idx < N_BUCKETS) s += cnt[idx];
        }
        csum[t] = s;
    }
    __syncthreads();
    if (t == 0) {
        int s = 0;
        for (int i = 0; i < 64; ++i) { int c = csum[i]; csum[i] = s; s += c; }
    }
    __syncthreads();
    if (t < 64) {
        int run = csum[t];
        for (int j = 0; j < 13; ++j) {
            int idx = t * 13 + j;
            if (idx < N_BUCKETS) { lbase[idx] = run; lcur[idx] = run; run += cnt[idx]; }
        }
    }
    __syncthreads();

    // ---- phase C: stage entries into LDS, grouped by bucket ----
    for (int k = 0; k < EPB; k += 1024) {
        int e = base + k + t;
        if (e < N_EDGES) {
            int r = rows[e];
            int b = r >> 6;
            int pos = atomicAdd(&lcur[b], 1);
            stageE[pos] = make_int2(
                (uint)cols[e] | ((uint)(r & 63) << 16) | ((uint)b << 22),
                __float_as_int(vals[e]));
        }
    }
    __syncthreads();

    // ---- phase D: coalesced flush (slot order == destination order) ----
    int total = lbase[N_BUCKETS - 1] + cnt[N_BUCKETS - 1];
    for (int k = 0; k < EPB; k += 1024) {
        int j = k + t;
        if (j < total) {
            int2 p = stageE[j];
            uint b = ((uint)p.x) >> 22;
            int pos = gbase[b] + (j - lbase[b]);
            if (pos < BUCKET_CAP)       // statistically impossible; safety
                perm[(size_t)b * BUCKET_CAP + pos] = p;   // agg masks b bits
        }
    }
}

// ---------------------------------------------------------------------------
// agg_fused: 2 blocks per bucket (512 thr, 32 rows each; grid 1564).
// Phase 1: single pass compacting into 32 per-row LDS lists.
// Phase 2: 4 rows/wave, bf16 gathers, unroll-8 ILP, fp32 reg accumulators.
// Phase 3: rows -> LDS (overlaying dead lists).
// Phase 4: 128x128 linear reading packed-bf16 W from GLOBAL (64 KB, L2-hot)
// + ReLU + LN -> out.  Dropping the 32 KB sW staging cuts LDS to 19.7 KB ->
// 4 blocks/CU = 32 waves/CU (vs R9's 15) for gather latency hiding.
// ---------------------------------------------------------------------------
__global__ __launch_bounds__(512, 8) void agg_fused(
    const int2* __restrict__ perm, const int* __restrict__ gcnt,
    const unsigned short* __restrict__ featb, const uint4* __restrict__ wpk,
    const float* __restrict__ bias, const float* __restrict__ scale,
    const float* __restrict__ offset, float* __restrict__ out)
{
    __shared__ int2 lists[32 * CAPR];    // 19456 B; rowsbuf (16 KB) overlays
    __shared__ int  lcnt[32];

    const int t = threadIdx.x;
    float* rowsbuf = (float*)lists;

    const int b  = blockIdx.x >> 1;
    const int lo = (blockIdx.x & 1) * 32;
    if (t < 32) lcnt[t] = 0;
    __syncthreads();

    int n = gcnt[b * GPAD];
    if (n > BUCKET_CAP) n = BUCKET_CAP;
    const int2* pb = perm + (size_t)b * BUCKET_CAP;

    for (int e = t; e < n; e += 512) {
        int2 p = pb[e];
        int rl = ((p.x >> 16) & 63) - lo;
        if ((uint)rl < 32u) {
            int pos = atomicAdd(&lcnt[rl], 1);
            if (pos < CAPR)
                lists[rl * CAPR + pos] = make_int2(p.x & 0xFFFF, p.y);
        }
    }
    __syncthreads();

    const int lane = t & 63;
    const int wid  = t >> 6;        // 0..7
    const int rb   = wid * 4;       // first local row of this wave

    float ax[4], ay[4];
    #pragma unroll
    for (int j = 0; j < 4; ++j) {
        int rl = rb + j;
        int cnt = lcnt[rl];
        if (cnt > CAPR) cnt = CAPR;
        const int2* L = &lists[rl * CAPR];
        float sx = 0.f, sy = 0.f;
        int e = 0;
        for (; e + 7 < cnt; e += 8) {
            int2 p[8]; uint g[8];
            #pragma unroll
            for (int k = 0; k < 8; ++k) p[k] = L[e + k];
            #pragma unroll
            for (int k = 0; k < 8; ++k)
                g[k] = ((const uint*)(featb + (size_t)p[k].x * DIM))[lane];
            #pragma unroll
            for (int k = 0; k < 8; ++k) {
                float v = __int_as_float(p[k].y);
                sx = fmaf(v, __uint_as_float(g[k] << 16), sx);
                sy = fmaf(v, __uint_as_float(g[k] & 0xFFFF0000u), sy);
            }
        }
        for (; e < cnt; ++e) {
            int2 p = L[e];
            uint g = ((const uint*)(featb + (size_t)p.x * DIM))[lane];
            float v = __int_as_float(p.y);
            sx = fmaf(v, __uint_as_float(g << 16), sx);
            sy = fmaf(v, __uint_as_float(g & 0xFFFF0000u), sy);
        }
        ax[j] = sx; ay[j] = sy;
    }
    __syncthreads();               // lists dead -> reuse as rowsbuf

    #pragma unroll
    for (int j = 0; j < 4; ++j)
        ((float2*)rowsbuf)[(rb + j) * 64 + lane] = make_float2(ax[j], ay[j]);
    __syncthreads();

    // ---- phase 4: linear + ReLU + LN for this wave's 4 rows ----
    const float bb0 = bias[lane],   bb1 = bias[lane + 64];
    const float sc0 = scale[lane],  sc1 = scale[lane + 64];
    const float of0 = offset[lane], of1 = offset[lane + 64];

    const float4* R0 = (const float4*)(rowsbuf + (rb + 0) * DIM);
    const float4* R1 = (const float4*)(rowsbuf + (rb + 1) * DIM);
    const float4* R2 = (const float4*)(rowsbuf + (rb + 2) * DIM);
    const float4* R3 = (const float4*)(rowsbuf + (rb + 3) * DIM);

    float x0 = bb0, y0 = bb1, x1 = bb0, y1 = bb1;
    float x2 = bb0, y2 = bb1, x3 = bb0, y3 = bb1;

    #pragma unroll 4
    for (int g = 0; g < 32; ++g) {
        uint4 wv = wpk[g * 64 + lane];     // global read, L2-hot 64 KB
        float4 a0 = R0[g], a1 = R1[g], a2 = R2[g], a3 = R3[g];
        float w0, w1;
        w0 = __uint_as_float(wv.x << 16); w1 = __uint_as_float(wv.x & 0xFFFF0000u);
        x0 = fmaf(a0.x, w0, x0);  y0 = fmaf(a0.x, w1, y0);
        x1 = fmaf(a1.x, w0, x1);  y1 = fmaf(a1.x, w1, y1);
        x2 = fmaf(a2.x, w0, x2);  y2 = fmaf(a2.x, w1, y2);
        x3 = fmaf(a3.x, w0, x3);  y3 = fmaf(a3.x, w1, y3);
        w0 = __uint_as_float(wv.y << 16); w1 = __uint_as_float(wv.y & 0xFFFF0000u);
        x0 = fmaf(a0.y, w0, x0);  y0 = fmaf(a0.y, w1, y0);
        x1 = fmaf(a1.y, w0, x1);  y1 = fmaf(a1.y, w1, y1);
        x2 = fmaf(a2.y, w0, x2);  y2 = fmaf(a2.y, w1, y2);
        x3 = fmaf(a3.y, w0, x3);  y3 = fmaf(a3.y, w1, y3);
        w0 = __uint_as_float(wv.z << 16); w1 = __uint_as_float(wv.z & 0xFFFF0000u);
        x0 = fmaf(a0.z, w0, x0);  y0 = fmaf(a0.z, w1, y0);
        x1 = fmaf(a1.z, w0, x1);  y1 = fmaf(a1.z, w1, y1);
        x2 = fmaf(a2.z, w0, x2);  y2 = fmaf(a2.z, w1, y2);
        x3 = fmaf(a3.z, w0, x3);  y3 = fmaf(a3.z, w1, y3);
        w0 = __uint_as_float(wv.w << 16); w1 = __uint_as_float(wv.w & 0xFFFF0000u);
        x0 = fmaf(a0.w, w0, x0);  y0 = fmaf(a0.w, w1, y0);
        x1 = fmaf(a1.w, w0, x1);  y1 = fmaf(a1.w, w1, y1);
        x2 = fmaf(a2.w, w0, x2);  y2 = fmaf(a2.w, w1, y2);
        x3 = fmaf(a3.w, w0, x3);  y3 = fmaf(a3.w, w1, y3);
    }

    #pragma unroll
    for (int j = 0; j < 4; ++j) {
        int r = b * ROWS_PER_BUCKET + lo + rb + j;
        if (r >= N_NODES) continue;                       // wave-uniform
        float A0 = (j == 0) ? x0 : (j == 1) ? x1 : (j == 2) ? x2 : x3;
        float A1 = (j == 0) ? y0 : (j == 1) ? y1 : (j == 2) ? y2 : y3;
        A0 = fmaxf(A0, 0.0f);
        A1 = fmaxf(A1, 0.0f);

        float s = A0 + A1;
        #pragma unroll
        for (int off = 32; off >= 1; off >>= 1) s += __shfl_xor(s, off, 64);
        float mean = s * (1.0f / 128.0f);

        float d0 = A0 - mean, d1 = A1 - mean;
        float q = d0 * d0 + d1 * d1;
        #pragma unroll
        for (int off = 32; off >= 1; off >>= 1) q += __shfl_xor(q, off, 64);
        float rstd = rsqrtf(q * (1.0f / 128.0f) + LN_EPS);

        size_t rowp = (size_t)r * DIM;
        out[rowp + lane]      = d0 * sc0 * rstd + of0;
        out[rowp + lane + 64] = d1 * sc1 * rstd + of1;
    }
}

extern "C" void kernel_launch(void* const* d_in, const int* in_sizes, int n_in,
                              void* d_out, int out_size, void* d_ws, size_t ws_size,
                              hipStream_t stream) {
    const float* feat_in = (const float*)d_in[0];
    const int*   rows    = (const int*)d_in[1];
    const int*   cols    = (const int*)d_in[2];
    const float* vals    = (const float*)d_in[3];
    const float* W       = (const float*)d_in[4];
    const float* bias    = (const float*)d_in[5];
    const float* scale   = (const float*)d_in[6];
    const float* offset  = (const float*)d_in[7];
    float* out = (float*)d_out;

    // ---- workspace layout ----
    char* p = (char*)d_ws;
    int2* perm = (int2*)p;                 p += (size_t)N_BUCKETS * BUCKET_CAP * 8; // 16.0 MB
    unsigned short* featb = (unsigned short*)p;
                                           p += (size_t)N_NODES * DIM * 2;          // 12.8 MB
    uint* wpk = (uint*)p;                  p += 32768;                              // 32 KB
    int*  gcnt = (int*)p;                  p += (size_t)N_BUCKETS * GPAD * 4;       // 50 KB padded

    hipMemsetAsync(gcnt, 0, (size_t)N_BUCKETS * GPAD * sizeof(int), stream);

    prep<<<SB + FCB + 1, 1024, 0, stream>>>(feat_in, W, rows, cols, vals,
                                            gcnt, perm, (uint*)featb, wpk);
    agg_fused<<<N_BUCKETS * 2, 512, 0, stream>>>(perm, gcnt, featb,
                                                 (const uint4*)wpk,
                                                 bias, scale, offset, out);
}